// Round 6
// baseline (24.379 us; speedup 1.0000x reference)
//
#include <hip/hip_runtime.h>

// x: (49, B*C=6, 256, 256) fp32; out: (6, 1024, 1024) fp32
// out[bc,h,w] = max over covering patches (i,j) of x[i*7+j, bc, h-128i, w-128j]
//
// Wave-uniform tiling: each 64-lane wave owns a 2-row x 128-col tile
//   lane>>5 = row parity, lane&31 = float4 column within the 128-band.
// Then hi=h>>7 and the j-band are IDENTICAL for all 64 lanes ->
// readfirstlane promotes them to SGPRs -> scalar branches, no exec-mask
// divergence, and each (i,j) load is 64 full lanes (two 512B segments).
//
// K=3 grid-strided chunks per thread differ ONLY in bc (+2 per chunk), so
// the (i,j)-class branch hoists out and the interior case issues 12
// back-to-back loads (max MLP).

typedef float v4f __attribute__((ext_vector_type(4)));

#define KCHUNK 3
#define NBLK   2048

__global__ __launch_bounds__(256) void unpatch_max_kernel(
    const float* __restrict__ x, float* __restrict__ out)
{
    const int tid  = blockIdx.x * 256 + threadIdx.x;
    const int lane = tid & 63;
    const int colq = lane & 31;          // float4 index within 128-col band
    const int rpar = lane >> 5;          // row within the 2-row pair

    // wave id in [0, 8192); uniform across the wave -> force to SGPR
    const int wid  = __builtin_amdgcn_readfirstlane(tid >> 6);
    const int band = wid & 7;            // 128-col band in [0,8)
    const int row2 = (wid >> 3) & 511;   // row pair in [0,512)
    const int bc0  = wid >> 12;          // in {0,1}; chunks add +2

    const int hi = row2 >> 6;            // == h>>7 for both rows of the pair
    const int i0 = hi - (hi > 0);
    const int j0 = band - (band > 0);
    const bool i2 = (hi > 0) & (hi < 7);     // two covering patch rows?
    const bool j2 = (band > 0) & (band < 7); // two covering patch cols?

    const int h = row2 * 2 + rpar;
    const int w = band * 128 + colq * 4;

    // float offsets
    const size_t DI = (size_t)7 * 6 * 65536 - 128 * 256;  // i0 -> i0+1
    const size_t DJ = (size_t)6 * 65536 - 128;            // j0 -> j0+1
    const size_t DB = (size_t)2 * 65536;                  // bc -> bc+2
    const size_t DO = (size_t)2 * 1024 * 1024;            // out: bc -> bc+2

    const float* p = x + (size_t)((i0 * 7 + j0) * 6 + bc0) * 65536
                       + (size_t)(h - i0 * 128) * 256 + (w - j0 * 128);
    float* o = out + (size_t)(bc0 * 1024 + h) * 1024 + w;

    if (i2 & j2) {
        #pragma unroll
        for (int k = 0; k < KCHUNK; ++k) {
            const float* pk = p + (size_t)k * DB;
            const v4f a = *reinterpret_cast<const v4f*>(pk);
            const v4f b = *reinterpret_cast<const v4f*>(pk + DJ);
            const v4f c = *reinterpret_cast<const v4f*>(pk + DI);
            const v4f d = *reinterpret_cast<const v4f*>(pk + DI + DJ);
            const v4f m = __builtin_elementwise_max(
                __builtin_elementwise_max(a, b),
                __builtin_elementwise_max(c, d));
            __builtin_nontemporal_store(m, reinterpret_cast<v4f*>(o + k * DO));
        }
    } else if (i2) {
        #pragma unroll
        for (int k = 0; k < KCHUNK; ++k) {
            const float* pk = p + (size_t)k * DB;
            const v4f a = *reinterpret_cast<const v4f*>(pk);
            const v4f c = *reinterpret_cast<const v4f*>(pk + DI);
            __builtin_nontemporal_store(__builtin_elementwise_max(a, c),
                                        reinterpret_cast<v4f*>(o + k * DO));
        }
    } else if (j2) {
        #pragma unroll
        for (int k = 0; k < KCHUNK; ++k) {
            const float* pk = p + (size_t)k * DB;
            const v4f a = *reinterpret_cast<const v4f*>(pk);
            const v4f b = *reinterpret_cast<const v4f*>(pk + DJ);
            __builtin_nontemporal_store(__builtin_elementwise_max(a, b),
                                        reinterpret_cast<v4f*>(o + k * DO));
        }
    } else {
        #pragma unroll
        for (int k = 0; k < KCHUNK; ++k) {
            const v4f a = *reinterpret_cast<const v4f*>(p + (size_t)k * DB);
            __builtin_nontemporal_store(a, reinterpret_cast<v4f*>(o + k * DO));
        }
    }
}

extern "C" void kernel_launch(void* const* d_in, const int* in_sizes, int n_in,
                              void* d_out, int out_size, void* d_ws, size_t ws_size,
                              hipStream_t stream)
{
    const float* x = (const float*)d_in[0];
    float* out = (float*)d_out;
    unpatch_max_kernel<<<NBLK, 256, 0, stream>>>(x, out);
}

// Round 7
// 22.511 us; speedup vs baseline: 1.0830x; 1.0830x over previous
//
#include <hip/hip_runtime.h>

// x: (49, B*C=6, 256, 256) fp32; out: (6, 1024, 1024) fp32
// out[bc,h,w] = max over covering patches (i,j) of x[i*7+j, bc, h-128i, w-128j]
//
// Wave-uniform tiling: each 64-lane wave owns a 2-row x 128-col tile
//   lane>>5 = row parity, lane&31 = float4 column within the 128-band.
// Then hi=h>>7 and the j-band are IDENTICAL for all 64 lanes ->
// readfirstlane promotes them to SGPRs -> scalar branches, no exec-mask
// divergence, and each (i,j) load is 64 full lanes (two 512B segments).
//
// K=3 grid-strided chunks per thread differ ONLY in bc (+2 per chunk), so
// the (i,j)-class branch hoists out and the interior case issues 12
// back-to-back loads (max MLP).

typedef float v4f __attribute__((ext_vector_type(4)));

#define KCHUNK 3
#define NBLK   2048

__global__ __launch_bounds__(256) void unpatch_max_kernel(
    const float* __restrict__ x, float* __restrict__ out)
{
    const int tid  = blockIdx.x * 256 + threadIdx.x;
    const int lane = tid & 63;
    const int colq = lane & 31;          // float4 index within 128-col band
    const int rpar = lane >> 5;          // row within the 2-row pair

    // wave id in [0, 8192); uniform across the wave -> force to SGPR
    const int wid  = __builtin_amdgcn_readfirstlane(tid >> 6);
    const int band = wid & 7;            // 128-col band in [0,8)
    const int row2 = (wid >> 3) & 511;   // row pair in [0,512)
    const int bc0  = wid >> 12;          // in {0,1}; chunks add +2

    const int hi = row2 >> 6;            // == h>>7 for both rows of the pair
    const int i0 = hi - (hi > 0);
    const int j0 = band - (band > 0);
    const bool i2 = (hi > 0) & (hi < 7);     // two covering patch rows?
    const bool j2 = (band > 0) & (band < 7); // two covering patch cols?

    const int h = row2 * 2 + rpar;
    const int w = band * 128 + colq * 4;

    // float offsets
    const size_t DI = (size_t)7 * 6 * 65536 - 128 * 256;  // i0 -> i0+1
    const size_t DJ = (size_t)6 * 65536 - 128;            // j0 -> j0+1
    const size_t DB = (size_t)2 * 65536;                  // bc -> bc+2
    const size_t DO = (size_t)2 * 1024 * 1024;            // out: bc -> bc+2

    const float* p = x + (size_t)((i0 * 7 + j0) * 6 + bc0) * 65536
                       + (size_t)(h - i0 * 128) * 256 + (w - j0 * 128);
    float* o = out + (size_t)(bc0 * 1024 + h) * 1024 + w;

    if (i2 & j2) {
        #pragma unroll
        for (int k = 0; k < KCHUNK; ++k) {
            const float* pk = p + (size_t)k * DB;
            const v4f a = *reinterpret_cast<const v4f*>(pk);
            const v4f b = *reinterpret_cast<const v4f*>(pk + DJ);
            const v4f c = *reinterpret_cast<const v4f*>(pk + DI);
            const v4f d = *reinterpret_cast<const v4f*>(pk + DI + DJ);
            const v4f m = __builtin_elementwise_max(
                __builtin_elementwise_max(a, b),
                __builtin_elementwise_max(c, d));
            __builtin_nontemporal_store(m, reinterpret_cast<v4f*>(o + k * DO));
        }
    } else if (i2) {
        #pragma unroll
        for (int k = 0; k < KCHUNK; ++k) {
            const float* pk = p + (size_t)k * DB;
            const v4f a = *reinterpret_cast<const v4f*>(pk);
            const v4f c = *reinterpret_cast<const v4f*>(pk + DI);
            __builtin_nontemporal_store(__builtin_elementwise_max(a, c),
                                        reinterpret_cast<v4f*>(o + k * DO));
        }
    } else if (j2) {
        #pragma unroll
        for (int k = 0; k < KCHUNK; ++k) {
            const float* pk = p + (size_t)k * DB;
            const v4f a = *reinterpret_cast<const v4f*>(pk);
            const v4f b = *reinterpret_cast<const v4f*>(pk + DJ);
            __builtin_nontemporal_store(__builtin_elementwise_max(a, b),
                                        reinterpret_cast<v4f*>(o + k * DO));
        }
    } else {
        #pragma unroll
        for (int k = 0; k < KCHUNK; ++k) {
            const v4f a = *reinterpret_cast<const v4f*>(p + (size_t)k * DB);
            __builtin_nontemporal_store(a, reinterpret_cast<v4f*>(o + k * DO));
        }
    }
}

extern "C" void kernel_launch(void* const* d_in, const int* in_sizes, int n_in,
                              void* d_out, int out_size, void* d_ws, size_t ws_size,
                              hipStream_t stream)
{
    const float* x = (const float*)d_in[0];
    float* out = (float*)d_out;
    unpatch_max_kernel<<<NBLK, 256, 0, stream>>>(x, out);
}

// Round 8
// 21.064 us; speedup vs baseline: 1.1574x; 1.0687x over previous
//
#include <hip/hip_runtime.h>

// x: (49, 6, 256, 256) fp32; out: (6, 1024, 1024) fp32
// out[bc,h,w] = max over covering patches (i,j) of x[i*7+j, bc, h-128i, w-128j]
//
// DRAM-burst version: each thread owns a 4-row x 4-col output quad
// (rows 4r..4r+3, same w). Per (i,j) stream the wave issues 4 back-to-back
// fully-coalesced 1 KB loads (patch row = 1 KB) = 4 KB contiguous per stream
// visit, instead of 1 KB + stream switch. Lane stride stays 16 B (R4 showed
// widening lane stride breaks coalescing). 4-aligned row quads never straddle
// the 128-row band boundary, so the covering class is uniform per thread.

typedef float v4f __attribute__((ext_vector_type(4)));

__global__ __launch_bounds__(64) void unpatch_max_kernel(
    const float* __restrict__ x, float* __restrict__ out)
{
    const int tid = blockIdx.x * 64 + threadIdx.x;    // [0, 393216)
    const int w4   = tid & 255;          // float4 col in [0,256)
    const int rest = tid >> 8;
    const int rq   = rest & 255;         // row quad in [0,256)
    const int bc   = rest >> 8;          // in [0,6)

    const int h0 = rq << 2;              // first of 4 rows
    const int w  = w4 << 2;

    const int hi = h0 >> 7;
    const int i1 = hi < 7 ? hi : 6;
    const int i0 = hi > 0 ? hi - 1 : 0;
    const int wi = w >> 7;
    const int j1 = wi < 7 ? wi : 6;
    const int j0 = wi > 0 ? wi - 1 : 0;

    v4f m0 = (v4f){-INFINITY, -INFINITY, -INFINITY, -INFINITY};
    v4f m1 = m0, m2 = m0, m3 = m0;

    #pragma unroll 2
    for (int i = i0; i <= i1; ++i) {
        const int ph0 = h0 - i * 128;                // in [0,256), 4-aligned
        #pragma unroll 2
        for (int j = j0; j <= j1; ++j) {
            const int pw  = w - j * 128;             // in [0,252], 4-aligned
            const float* p = x +
                ((size_t)((i * 7 + j) * 6 + bc) << 16) + (size_t)ph0 * 256 + pw;
            // 4 consecutive patch rows -> 4 KB contiguous per wave
            const v4f a0 = *reinterpret_cast<const v4f*>(p);
            const v4f a1 = *reinterpret_cast<const v4f*>(p + 256);
            const v4f a2 = *reinterpret_cast<const v4f*>(p + 512);
            const v4f a3 = *reinterpret_cast<const v4f*>(p + 768);
            m0 = __builtin_elementwise_max(m0, a0);
            m1 = __builtin_elementwise_max(m1, a1);
            m2 = __builtin_elementwise_max(m2, a2);
            m3 = __builtin_elementwise_max(m3, a3);
        }
    }

    float* o = out + ((size_t)bc << 20) + (size_t)h0 * 1024 + w;
    __builtin_nontemporal_store(m0, reinterpret_cast<v4f*>(o));
    __builtin_nontemporal_store(m1, reinterpret_cast<v4f*>(o + 1024));
    __builtin_nontemporal_store(m2, reinterpret_cast<v4f*>(o + 2048));
    __builtin_nontemporal_store(m3, reinterpret_cast<v4f*>(o + 3072));
}

extern "C" void kernel_launch(void* const* d_in, const int* in_sizes, int n_in,
                              void* d_out, int out_size, void* d_ws, size_t ws_size,
                              hipStream_t stream)
{
    const float* x = (const float*)d_in[0];
    float* out = (float*)d_out;

    // 393216 threads / 64 = 6144 single-wave blocks (fine-grained scheduling,
    // no occupancy-quantization cliff).
    unpatch_max_kernel<<<6144, 64, 0, stream>>>(x, out);
}